// Round 4
// baseline (92.504 us; speedup 1.0000x reference)
//
#include <hip/hip_runtime.h>
#include <math.h>

#define NB 4096
#define NIN 128
#define NH 256
#define ND 32
#define NC 8
#define NK 256
#define NHS 16

// output offsets (in floats), concatenated in reference return order
#define OFF_KCHART 0
#define OFF_KCODE  4096
#define OFF_ZN     8192
#define OFF_ZTEX   (OFF_ZN + 4096*32)        // 139264
#define OFF_ROUTER (OFF_ZTEX + 4096*32)      // 270336 (float4-aligned)
#define OFF_ZGEO   (OFF_ROUTER + 4096*8)     // 303104
#define OFF_LOSS   (OFF_ZGEO + 4096*32)      // 434176
#define OFF_IND    (OFF_LOSS + 1)            // 434177 (odd -> scalar access only)
#define OFF_ZNALL  (OFF_IND + 4096*8)        // 466945 (odd -> scalar access only)
#define OFF_CBAR   (OFF_ZNALL + 4096*8*32)   // 1515521 (odd -> scalar)
#define OFF_VLOC   (OFF_CBAR + 4096*32)      // 1646593 (odd -> scalar)

__device__ __forceinline__ float gelu_exact(float x) {
    return x * (erff(x / 1.41421356237309504f) + 1.0f) * 0.5f;
}

// ---------------------------------------------------------------------------
// Fused encoder: per block = 16 rows.
//   h1 = gelu(x@W1+b1)   (K=128, LDS-tiled W1, A transposed in LDS)
//   feats = gelu(h1@W2+b2) (K=256)
//   v = feats@Wv+bv ; scores ; softmax router ; K_chart ; c_bar ; v_local
// 256 threads: rg = t>>5 (2 rows each), cg = t&31 (8 cols each) for GEMMs.
// ---------------------------------------------------------------------------
__global__ __launch_bounds__(256, 1)
void encoder_kernel(const float* __restrict__ x, const float* __restrict__ W1,
                    const float* __restrict__ b1, const float* __restrict__ W2,
                    const float* __restrict__ b2, const float* __restrict__ Wv,
                    const float* __restrict__ bv, const float* __restrict__ centers,
                    float* __restrict__ out, float* __restrict__ vloc_ws) {
    __shared__ float sAT[256][18];   // [k][row]; x (k<128), then h1
    __shared__ float sW[32][260];    // W k-tile [k][col]; later WvT [c][k]
    __shared__ float sFR[16][260];   // feats row-major
    __shared__ float sVv[16][34];
    __shared__ float sCent[256];
    __shared__ float sScore[16][8];
    __shared__ float sRout[16][8];
    const int t = threadIdx.x;
    const int row0 = blockIdx.x * 16;
    const int rg = t >> 5;
    const int cg = t & 31;

    // stage x transposed (16x128 -> sAT[k][row])
    #pragma unroll
    for (int q = 0; q < 2; q++) {
        int id = q * 256 + t;
        int row = id >> 5, f = id & 31;
        float4 a = *(const float4*)(x + (row0 + row) * NIN + f * 4);
        sAT[f*4+0][row] = a.x; sAT[f*4+1][row] = a.y;
        sAT[f*4+2][row] = a.z; sAT[f*4+3][row] = a.w;
    }
    if (t < 64) ((float4*)sCent)[t] = ((const float4*)centers)[t];

    // ---- GEMM1: K=128, 4 tiles of BK=32 ----
    float4 pw[8];
    #pragma unroll
    for (int q = 0; q < 8; q++) {
        int id = q * 256 + t; int kr = id >> 6, c4 = (id & 63) * 4;
        pw[q] = *(const float4*)(W1 + kr * NH + c4);
    }
    float acc[2][8];
    #pragma unroll
    for (int i = 0; i < 2; i++)
        #pragma unroll
        for (int j = 0; j < 8; j++) acc[i][j] = 0.f;

    for (int tile = 0; tile < 4; tile++) {
        __syncthreads();
        #pragma unroll
        for (int q = 0; q < 8; q++) {
            int id = q * 256 + t; int kr = id >> 6, c4 = (id & 63) * 4;
            *(float4*)(&sW[kr][c4]) = pw[q];
        }
        __syncthreads();
        if (tile < 3) {
            #pragma unroll
            for (int q = 0; q < 8; q++) {
                int id = q * 256 + t; int kr = id >> 6, c4 = (id & 63) * 4;
                pw[q] = *(const float4*)(W1 + (tile * 32 + 32 + kr) * NH + c4);
            }
        }
        #pragma unroll
        for (int k = 0; k < 32; k++) {
            float2 a = *(const float2*)(&sAT[tile * 32 + k][rg * 2]);
            float4 w0 = *(const float4*)(&sW[k][cg * 8]);
            float4 w1 = *(const float4*)(&sW[k][cg * 8 + 4]);
            float wv[8] = {w0.x, w0.y, w0.z, w0.w, w1.x, w1.y, w1.z, w1.w};
            #pragma unroll
            for (int j = 0; j < 8; j++) {
                acc[0][j] = fmaf(a.x, wv[j], acc[0][j]);
                acc[1][j] = fmaf(a.y, wv[j], acc[1][j]);
            }
        }
    }

    // prefetch W2 tile 0 while writing h1
    #pragma unroll
    for (int q = 0; q < 8; q++) {
        int id = q * 256 + t; int kr = id >> 6, c4 = (id & 63) * 4;
        pw[q] = *(const float4*)(W2 + kr * NH + c4);
    }
    {
        float4 bA = *(const float4*)(b1 + cg * 8);
        float4 bB = *(const float4*)(b1 + cg * 8 + 4);
        float bb[8] = {bA.x, bA.y, bA.z, bA.w, bB.x, bB.y, bB.z, bB.w};
        __syncthreads();   // all waves done reading x from sAT
        #pragma unroll
        for (int i = 0; i < 2; i++)
            #pragma unroll
            for (int j = 0; j < 8; j++)
                sAT[cg * 8 + j][rg * 2 + i] = gelu_exact(acc[i][j] + bb[j]);
    }

    // ---- GEMM2: K=256, 8 tiles ----
    float acc2[2][8];
    #pragma unroll
    for (int i = 0; i < 2; i++)
        #pragma unroll
        for (int j = 0; j < 8; j++) acc2[i][j] = 0.f;

    for (int tile = 0; tile < 8; tile++) {
        __syncthreads();
        #pragma unroll
        for (int q = 0; q < 8; q++) {
            int id = q * 256 + t; int kr = id >> 6, c4 = (id & 63) * 4;
            *(float4*)(&sW[kr][c4]) = pw[q];
        }
        __syncthreads();
        if (tile < 7) {
            #pragma unroll
            for (int q = 0; q < 8; q++) {
                int id = q * 256 + t; int kr = id >> 6, c4 = (id & 63) * 4;
                pw[q] = *(const float4*)(W2 + (tile * 32 + 32 + kr) * NH + c4);
            }
        }
        #pragma unroll
        for (int k = 0; k < 32; k++) {
            float2 a = *(const float2*)(&sAT[tile * 32 + k][rg * 2]);
            float4 w0 = *(const float4*)(&sW[k][cg * 8]);
            float4 w1 = *(const float4*)(&sW[k][cg * 8 + 4]);
            float wv[8] = {w0.x, w0.y, w0.z, w0.w, w1.x, w1.y, w1.z, w1.w};
            #pragma unroll
            for (int j = 0; j < 8; j++) {
                acc2[0][j] = fmaf(a.x, wv[j], acc2[0][j]);
                acc2[1][j] = fmaf(a.y, wv[j], acc2[1][j]);
            }
        }
    }
    {
        float4 bA = *(const float4*)(b2 + cg * 8);
        float4 bB = *(const float4*)(b2 + cg * 8 + 4);
        float bb[8] = {bA.x, bA.y, bA.z, bA.w, bB.x, bB.y, bB.z, bB.w};
        #pragma unroll
        for (int i = 0; i < 2; i++)
            #pragma unroll
            for (int j = 0; j < 8; j++)
                sFR[rg * 2 + i][cg * 8 + j] = gelu_exact(acc2[i][j] + bb[j]);
    }
    __syncthreads();   // GEMM2 sW reads done; sFR written
    // stage Wv transposed into sW as [c][k]
    #pragma unroll
    for (int q = 0; q < 8; q++) {
        int id = q * 256 + t; int k = id >> 3, c4 = (id & 7) * 4;
        float4 w = *(const float4*)(Wv + k * ND + c4);
        sW[c4+0][k] = w.x; sW[c4+1][k] = w.y; sW[c4+2][k] = w.z; sW[c4+3][k] = w.w;
    }
    __syncthreads();
    // ---- v = feats @ Wv + bv ----
    {
        const int r = t >> 4, i = t & 15;
        const int c0 = (i & 7) * 4, kh = i >> 3;
        float va[4] = {0.f, 0.f, 0.f, 0.f};
        #pragma unroll
        for (int k4 = 0; k4 < 32; k4++) {
            int k = kh * 128 + k4 * 4;
            float4 fa = *(const float4*)(&sFR[r][k]);
            #pragma unroll
            for (int cj = 0; cj < 4; cj++) {
                float4 w = *(const float4*)(&sW[c0 + cj][k]);
                va[cj] = fmaf(fa.x, w.x, va[cj]);
                va[cj] = fmaf(fa.y, w.y, va[cj]);
                va[cj] = fmaf(fa.z, w.z, va[cj]);
                va[cj] = fmaf(fa.w, w.w, va[cj]);
            }
        }
        #pragma unroll
        for (int cj = 0; cj < 4; cj++) va[cj] += __shfl_xor(va[cj], 8, 16);
        if (kh == 0) {
            #pragma unroll
            for (int cj = 0; cj < 4; cj++) sVv[r][c0 + cj] = va[cj] + bv[c0 + cj];
        }
    }
    __syncthreads();
    // ---- scores ----
    if (t < 128) {
        int r = t >> 3, c = t & 7;
        float s = 0.f;
        #pragma unroll
        for (int k = 0; k < ND; k++) s = fmaf(sVv[r][k], sCent[c * ND + k], s);
        sScore[r][c] = s / 5.65685424949238f;
    }
    __syncthreads();
    // ---- softmax / K_chart ----
    if (t < 16) {
        const int rr = t, grow = row0 + rr;
        float sc[NC];
        float m = -3.4e38f; int kmax = 0;
        #pragma unroll
        for (int c = 0; c < NC; c++) {
            float s = sScore[rr][c];
            sc[c] = s;
            if (s > m) { m = s; kmax = c; }
        }
        float ssum = 0.f;
        #pragma unroll
        for (int c = 0; c < NC; c++) { float e = expf(sc[c] - m); sc[c] = e; ssum += e; }
        float inv = 1.f / ssum;
        #pragma unroll
        for (int c = 0; c < NC; c++) {
            float rv = sc[c] * inv;
            sRout[rr][c] = rv;
            out[OFF_ROUTER + grow * NC + c] = rv;
        }
        out[OFF_KCHART + grow] = (float)kmax;
    }
    __syncthreads();
    // ---- c_bar / v_local ----
    {
        const int r = t >> 4, i = t & 15;
        const int row = row0 + r;
        #pragma unroll
        for (int j = 0; j < 2; j++) {
            int col = 2 * i + j;
            float cb = 0.f;
            #pragma unroll
            for (int c = 0; c < NC; c++) cb = fmaf(sRout[r][c], sCent[c * ND + col], cb);
            float vl = sVv[r][col] - cb;
            out[OFF_CBAR + row * ND + col] = cb;
            out[OFF_VLOC + row * ND + col] = vl;
            vloc_ws[row * ND + col] = vl;
        }
    }
}

// ---------------------------------------------------------------------------
// vq_chart: block = 64 rows x 1 chart. grid 512 (rowtile, chart).
// ---------------------------------------------------------------------------
__global__ __launch_bounds__(256)
void vq_chart(const float* __restrict__ codebook, const float* __restrict__ vloc_ws,
              const float* __restrict__ Ws1, const float* __restrict__ bs1,
              const float* __restrict__ Ws2, const float* __restrict__ bs2,
              float* __restrict__ out, float* __restrict__ loss_partial) {
    __shared__ float sCB[NK][36];
    __shared__ float sV[64][36];
    __shared__ float sBest[8][64];
    __shared__ int   sBidx[8][64];
    __shared__ int   sSel[64];
    __shared__ float sRoutv[64];
    __shared__ float sPscale[64];
    __shared__ float sLossArr[64];
    __shared__ float sWs1[ND][17];
    __shared__ float sWs2[NHS][33];
    __shared__ float sbs1[NHS], sbs2v[ND];
    const int t = threadIdx.x;
    const int c = blockIdx.x & 7;
    const int row0 = (blockIdx.x >> 3) * 64;

    {
        const float4* src = (const float4*)(codebook + c * NK * ND);
        #pragma unroll
        for (int q = 0; q < 8; q++) {
            int id = t + q * 256;
            int code = id >> 3, kq = (id & 7) * 4;
            *(float4*)(&sCB[code][kq]) = src[id];
        }
        #pragma unroll
        for (int q = 0; q < 2; q++) {
            int id = t + q * 256;
            int rr = id >> 3, kq = (id & 7) * 4;
            *(float4*)(&sV[rr][kq]) = ((const float4*)(vloc_ws + row0 * ND))[id];
        }
    }
    if (t < 128) {
        float4 w = ((const float4*)Ws1)[t];
        int k = t >> 2, o = (t & 3) * 4;
        sWs1[k][o] = w.x; sWs1[k][o+1] = w.y; sWs1[k][o+2] = w.z; sWs1[k][o+3] = w.w;
    } else {
        int u = t - 128;
        float4 w = ((const float4*)Ws2)[u];
        int k = u >> 3, o = (u & 7) * 4;
        sWs2[k][o] = w.x; sWs2[k][o+1] = w.y; sWs2[k][o+2] = w.z; sWs2[k][o+3] = w.w;
    }
    if (t < NHS) sbs1[t] = bs1[t];
    else if (t < NHS + ND) sbs2v[t - NHS] = bs2[t - NHS];
    if (t < 64) sRoutv[t] = out[OFF_ROUTER + (row0 + t) * NC + c];
    __syncthreads();

    const int r = t & 31, g = t >> 5;
    float vl0[ND], vl1[ND];
    #pragma unroll
    for (int q = 0; q < 8; q++) {
        float4 a = *(const float4*)(&sV[r][q * 4]);
        vl0[q*4] = a.x; vl0[q*4+1] = a.y; vl0[q*4+2] = a.z; vl0[q*4+3] = a.w;
        float4 b = *(const float4*)(&sV[r + 32][q * 4]);
        vl1[q*4] = b.x; vl1[q*4+1] = b.y; vl1[q*4+2] = b.z; vl1[q*4+3] = b.w;
    }
    float best0 = 3.4e38f, best1 = 3.4e38f;
    int bi0 = 0, bi1 = 0;
    for (int j = 0; j < 32; j++) {
        const int code = g * 32 + j;
        float dot0 = 0.f, dot1 = 0.f, en2 = 0.f;
        #pragma unroll
        for (int q = 0; q < 8; q++) {
            float4 e = *(const float4*)(&sCB[code][q * 4]);
            en2  = fmaf(e.x, e.x, en2);
            dot0 = fmaf(vl0[q*4+0], e.x, dot0); dot1 = fmaf(vl1[q*4+0], e.x, dot1);
            en2  = fmaf(e.y, e.y, en2);
            dot0 = fmaf(vl0[q*4+1], e.y, dot0); dot1 = fmaf(vl1[q*4+1], e.y, dot1);
            en2  = fmaf(e.z, e.z, en2);
            dot0 = fmaf(vl0[q*4+2], e.z, dot0); dot1 = fmaf(vl1[q*4+2], e.z, dot1);
            en2  = fmaf(e.w, e.w, en2);
            dot0 = fmaf(vl0[q*4+3], e.w, dot0); dot1 = fmaf(vl1[q*4+3], e.w, dot1);
        }
        float d0 = en2 - 2.f * dot0;
        float d1 = en2 - 2.f * dot1;
        if (d0 < best0) { best0 = d0; bi0 = code; }
        if (d1 < best1) { best1 = d1; bi1 = code; }
    }
    sBest[g][r] = best0;      sBidx[g][r] = bi0;
    sBest[g][r + 32] = best1; sBidx[g][r + 32] = bi1;
    __syncthreads();
    if (t < 64) {
        float bb = sBest[0][t]; int ii = sBidx[0][t];
        #pragma unroll
        for (int gg = 1; gg < 8; gg++) {
            float v = sBest[gg][t];
            if (v < bb) { bb = v; ii = sBidx[gg][t]; }
        }
        sSel[t] = ii;
        out[OFF_IND + (row0 + t) * NC + c] = (float)ii;
        float vn2 = 0.f;
        #pragma unroll
        for (int k = 0; k < ND; k++) { float v = sV[t][k]; vn2 = fmaf(v, v, vn2); }
        float norm = fmaxf(sqrtf(vn2), 1e-6f);
        sPscale[t] = fminf(0.99f / norm, 1.0f);
    }
    __syncthreads();

    const int i = t & 15, r16 = t >> 4;
    const float b1r = sbs1[i];
    const float bo0 = sbs2v[2*i], bo1 = sbs2v[2*i+1];
    #pragma unroll
    for (int pass = 0; pass < 4; pass++) {
        const int lrow = pass * 16 + r16;
        const int grow = row0 + lrow;
        const int sel = sSel[lrow];
        const float rc = sRoutv[lrow];
        const float ps = sPscale[lrow];
        float acc1 = b1r;
        #pragma unroll
        for (int k = 0; k < ND; k++) {
            float dlt = sV[lrow][k] - sCB[sel][k];
            acc1 = fmaf(dlt, sWs1[k][i], acc1);
        }
        float h = gelu_exact(acc1);
        float a0 = bo0, a1 = bo1;
        #pragma unroll
        for (int k = 0; k < NHS; k++) {
            float s1k = __shfl(h, k, 16);
            a0 = fmaf(s1k, sWs2[k][2*i],   a0);
            a1 = fmaf(s1k, sWs2[k][2*i+1], a1);
        }
        out[OFF_ZNALL + (grow * NC + c) * ND + 2*i]     = a0;
        out[OFF_ZNALL + (grow * NC + c) * ND + 2*i + 1] = a1;
        const float e0 = sCB[sel][2*i], e1 = sCB[sel][2*i+1];
        float yp0 = sV[lrow][2*i] * ps, yp1 = sV[lrow][2*i+1] * ps;
        float d0 = e0 - yp0, d1 = e1 - yp1;
        float sq = fmaf(d0, d0, d1 * d1);
        float xn = fmaf(e0, e0, e1 * e1);
        float yn = fmaf(yp0, yp0, yp1 * yp1);
        #pragma unroll
        for (int m = 1; m < 16; m <<= 1) {
            sq += __shfl_xor(sq, m, 16);
            xn += __shfl_xor(xn, m, 16);
            yn += __shfl_xor(yn, m, 16);
        }
        if (i == 0) {
            float denom = fmaxf((1.f - xn) * (1.f - yn), 1e-6f);
            float arg = fmaxf(1.f + 2.f * sq / denom, 1.f + 1e-6f);
            float dd = acoshf(arg);
            sLossArr[lrow] = dd * dd * rc;
        }
    }
    __syncthreads();
    if (t < 64) {
        float v = sLossArr[t];
        #pragma unroll
        for (int off = 32; off > 0; off >>= 1) v += __shfl_down(v, off, 64);
        if (t == 0) loss_partial[blockIdx.x] = v;
    }
}

// ---------------------------------------------------------------------------
// finalize + loss reduce (block 0): blends + z_n/z_tex/z_geo + K_code.
// ---------------------------------------------------------------------------
__global__ __launch_bounds__(256)
void finalize2_kernel(const float* __restrict__ codebook, const float* __restrict__ vloc_ws,
                      float* __restrict__ out, const float* __restrict__ partials) {
    const int gid = blockIdx.x * 256 + threadIdx.x;
    const int row = gid >> 4;
    const int cp = gid & 15;
    float rout[NC]; int ind[NC];
    #pragma unroll
    for (int cc = 0; cc < NC; cc++) {
        rout[cc] = out[OFF_ROUTER + row * NC + cc];
        ind[cc]  = (int)out[OFF_IND + row * NC + cc];
    }
    float zn0 = 0.f, zn1 = 0.f, zq0 = 0.f, zq1 = 0.f;
    #pragma unroll
    for (int cc = 0; cc < NC; cc++) {
        const float rcc = rout[cc];
        zn0 = fmaf(out[OFF_ZNALL + (row * NC + cc) * ND + 2*cp],     rcc, zn0);
        zn1 = fmaf(out[OFF_ZNALL + (row * NC + cc) * ND + 2*cp + 1], rcc, zn1);
        const float* e = codebook + (cc * NK + ind[cc]) * ND + 2*cp;
        zq0 = fmaf(e[0], rcc, zq0);
        zq1 = fmaf(e[1], rcc, zq1);
    }
    const float v0 = vloc_ws[row * ND + 2*cp], v1 = vloc_ws[row * ND + 2*cp + 1];
    const float cb0 = out[OFF_CBAR + row * ND + 2*cp];
    const float cb1 = out[OFF_CBAR + row * ND + 2*cp + 1];
    out[OFF_ZN   + row * ND + 2*cp]     = zn0;
    out[OFF_ZN   + row * ND + 2*cp + 1] = zn1;
    out[OFF_ZTEX + row * ND + 2*cp]     = v0 - zq0 - zn0;
    out[OFF_ZTEX + row * ND + 2*cp + 1] = v1 - zq1 - zn1;
    out[OFF_ZGEO + row * ND + 2*cp]     = cb0 + zq0 + zn0;
    out[OFF_ZGEO + row * ND + 2*cp + 1] = cb1 + zq1 + zn1;
    if (cp == 0) {
        int kc = (int)out[OFF_KCHART + row];
        out[OFF_KCODE + row] = out[OFF_IND + row * NC + kc];
    }
    if (blockIdx.x == 0) {
        __shared__ float sTmp[4];
        const int t = threadIdx.x;
        float v = partials[t] + partials[t + 256];
        #pragma unroll
        for (int off = 32; off > 0; off >>= 1) v += __shfl_down(v, off, 64);
        if ((t & 63) == 0) sTmp[t >> 6] = v;
        __syncthreads();
        if (t == 0) out[OFF_LOSS] = 1.25f * (sTmp[0] + sTmp[1] + sTmp[2] + sTmp[3]) / 4096.f;
    }
}

extern "C" void kernel_launch(void* const* d_in, const int* in_sizes, int n_in,
                              void* d_out, int out_size, void* d_ws, size_t ws_size,
                              hipStream_t stream) {
    const float* x        = (const float*)d_in[0];
    const float* W1       = (const float*)d_in[1];
    const float* b1       = (const float*)d_in[2];
    const float* W2       = (const float*)d_in[3];
    const float* b2       = (const float*)d_in[4];
    const float* Wv       = (const float*)d_in[5];
    const float* bv       = (const float*)d_in[6];
    const float* centers  = (const float*)d_in[7];
    const float* codebook = (const float*)d_in[8];
    const float* Ws1      = (const float*)d_in[9];
    const float* bs1      = (const float*)d_in[10];
    const float* Ws2      = (const float*)d_in[11];
    const float* bs2      = (const float*)d_in[12];
    float* out = (float*)d_out;
    float* ws  = (float*)d_ws;

    float* vloc     = ws;                // 4096*32
    float* partials = ws + 4096 * 32;    // 512

    encoder_kernel<<<dim3(256), dim3(256), 0, stream>>>(x, W1, b1, W2, b2, Wv, bv, centers, out, vloc);
    vq_chart<<<dim3(512), dim3(256), 0, stream>>>(codebook, vloc, Ws1, bs1, Ws2, bs2, out, partials);
    finalize2_kernel<<<dim3(256), dim3(256), 0, stream>>>(codebook, vloc, out, partials);
}

// Round 5
// 69.595 us; speedup vs baseline: 1.3292x; 1.3292x over previous
//
#include <hip/hip_runtime.h>
#include <math.h>

#define NB 4096
#define NIN 128
#define NH 256
#define ND 32
#define NC 8
#define NK 256
#define NHS 16

// output offsets (in floats), concatenated in reference return order
#define OFF_KCHART 0
#define OFF_KCODE  4096
#define OFF_ZN     8192
#define OFF_ZTEX   (OFF_ZN + 4096*32)        // 139264
#define OFF_ROUTER (OFF_ZTEX + 4096*32)      // 270336 (float4-aligned)
#define OFF_ZGEO   (OFF_ROUTER + 4096*8)     // 303104
#define OFF_LOSS   (OFF_ZGEO + 4096*32)      // 434176
#define OFF_IND    (OFF_LOSS + 1)            // 434177 (odd -> scalar access only)
#define OFF_ZNALL  (OFF_IND + 4096*8)        // 466945 (odd -> scalar access only)
#define OFF_CBAR   (OFF_ZNALL + 4096*8*32)   // 1515521 (odd -> scalar)
#define OFF_VLOC   (OFF_CBAR + 4096*32)      // 1646593 (odd -> scalar)

__device__ __forceinline__ float gelu_exact(float x) {
    return x * (erff(x / 1.41421356237309504f) + 1.0f) * 0.5f;
}

// ---------------------------------------------------------------------------
// GEMM v2: out = gelu(A[M][K] @ W[K][256] + b). 64x64 tile, 256 thr, 4x4
// micro. B in LDS (double-buffered, ONE barrier/tile); A streamed from
// global into registers (4 rows x 4-k chunks, prefetch depth 2).
// LDS bytes/FMA halved vs r3 (was 3:1 LDS-bound).
// ---------------------------------------------------------------------------
template<int K>
__global__ __launch_bounds__(256)
void gemm_bias_gelu(const float* __restrict__ A, const float* __restrict__ W,
                    const float* __restrict__ bias, float* __restrict__ out) {
    const int N = 256;
    __shared__ float sB[2][32][68];   // [buf][k][col], pad 68 (2-way free)
    const int t  = threadIdx.x;
    const int n0 = blockIdx.x * 64;
    const int r0 = blockIdx.y * 64;
    const int ty = t >> 4, tx = t & 15;
    const int bk = t >> 4, bc = t & 15;   // B staging: 2 float4/thread

    float4 bias4 = *(const float4*)(bias + n0 + tx * 4);

    // B tile 0 prefetch (regs)
    float4 pb0 = *(const float4*)(W + bk * N + n0 + bc * 4);
    float4 pb1 = *(const float4*)(W + (bk + 16) * N + n0 + bc * 4);

    // A stream: 4 row base pointers, chunks of 4 k
    const float* Ab0 = A + (r0 + ty * 4 + 0) * K;
    const float* Ab1 = A + (r0 + ty * 4 + 1) * K;
    const float* Ab2 = A + (r0 + ty * 4 + 2) * K;
    const float* Ab3 = A + (r0 + ty * 4 + 3) * K;
    float ac[4][4], an[4][4];
    {
        float4 c0 = *(const float4*)(Ab0 + 0), c1 = *(const float4*)(Ab1 + 0);
        float4 c2 = *(const float4*)(Ab2 + 0), c3 = *(const float4*)(Ab3 + 0);
        ac[0][0]=c0.x; ac[0][1]=c0.y; ac[0][2]=c0.z; ac[0][3]=c0.w;
        ac[1][0]=c1.x; ac[1][1]=c1.y; ac[1][2]=c1.z; ac[1][3]=c1.w;
        ac[2][0]=c2.x; ac[2][1]=c2.y; ac[2][2]=c2.z; ac[2][3]=c2.w;
        ac[3][0]=c3.x; ac[3][1]=c3.y; ac[3][2]=c3.z; ac[3][3]=c3.w;
        float4 n0v = *(const float4*)(Ab0 + 4), n1v = *(const float4*)(Ab1 + 4);
        float4 n2v = *(const float4*)(Ab2 + 4), n3v = *(const float4*)(Ab3 + 4);
        an[0][0]=n0v.x; an[0][1]=n0v.y; an[0][2]=n0v.z; an[0][3]=n0v.w;
        an[1][0]=n1v.x; an[1][1]=n1v.y; an[1][2]=n1v.z; an[1][3]=n1v.w;
        an[2][0]=n2v.x; an[2][1]=n2v.y; an[2][2]=n2v.z; an[2][3]=n2v.w;
        an[3][0]=n3v.x; an[3][1]=n3v.y; an[3][2]=n3v.z; an[3][3]=n3v.w;
    }

    float acc[4][4];
    #pragma unroll
    for (int i = 0; i < 4; i++)
        #pragma unroll
        for (int j = 0; j < 4; j++) acc[i][j] = 0.f;

    int buf = 0;
    for (int kk = 0; kk < K; kk += 32) {
        // regs -> LDS (other buffer is still being read only in prior iter)
        *(float4*)(&sB[buf][bk][bc*4])    = pb0;
        *(float4*)(&sB[buf][bk+16][bc*4]) = pb1;
        __syncthreads();
        if (kk + 32 < K) {
            pb0 = *(const float4*)(W + (kk + 32 + bk) * N + n0 + bc * 4);
            pb1 = *(const float4*)(W + (kk + 32 + bk + 16) * N + n0 + bc * 4);
        }
        #pragma unroll
        for (int c = 0; c < 8; c++) {
            // prefetch A chunk c+2 (clamped at array end; extra load harmless)
            int knext = kk + (c + 2) * 4;
            if (knext > K - 4) knext = K - 4;
            float4 p0 = *(const float4*)(Ab0 + knext);
            float4 p1 = *(const float4*)(Ab1 + knext);
            float4 p2 = *(const float4*)(Ab2 + knext);
            float4 p3 = *(const float4*)(Ab3 + knext);
            // compute 4 k-steps from ac
            #pragma unroll
            for (int u = 0; u < 4; u++) {
                float4 bv = *(const float4*)(&sB[buf][c * 4 + u][tx * 4]);
                float bb[4] = {bv.x, bv.y, bv.z, bv.w};
                #pragma unroll
                for (int j = 0; j < 4; j++) {
                    acc[0][j] = fmaf(ac[0][u], bb[j], acc[0][j]);
                    acc[1][j] = fmaf(ac[1][u], bb[j], acc[1][j]);
                    acc[2][j] = fmaf(ac[2][u], bb[j], acc[2][j]);
                    acc[3][j] = fmaf(ac[3][u], bb[j], acc[3][j]);
                }
            }
            // rotate: ac <- an <- p
            #pragma unroll
            for (int u = 0; u < 4; u++) {
                ac[0][u] = an[0][u]; ac[1][u] = an[1][u];
                ac[2][u] = an[2][u]; ac[3][u] = an[3][u];
            }
            an[0][0]=p0.x; an[0][1]=p0.y; an[0][2]=p0.z; an[0][3]=p0.w;
            an[1][0]=p1.x; an[1][1]=p1.y; an[1][2]=p1.z; an[1][3]=p1.w;
            an[2][0]=p2.x; an[2][1]=p2.y; an[2][2]=p2.z; an[2][3]=p2.w;
            an[3][0]=p3.x; an[3][1]=p3.y; an[3][2]=p3.z; an[3][3]=p3.w;
        }
        buf ^= 1;
    }
    float bb4[4] = {bias4.x, bias4.y, bias4.z, bias4.w};
    #pragma unroll
    for (int i = 0; i < 4; i++) {
        int row = r0 + ty * 4 + i;
        float4 o;
        float* op = (float*)&o;
        #pragma unroll
        for (int j = 0; j < 4; j++) op[j] = gelu_exact(acc[i][j] + bb4[j]);
        *(float4*)(out + row * N + n0 + tx * 4) = o;
    }
}

// ---------------------------------------------------------------------------
// v = feats@Wv + bv ; softmax router ; K_chart ; c_bar ; v_local
// ---------------------------------------------------------------------------
__global__ __launch_bounds__(256)
void router_kernel(const float* __restrict__ feats, const float* __restrict__ Wv,
                   const float* __restrict__ bv, const float* __restrict__ centers,
                   float* __restrict__ out, float* __restrict__ vloc_ws) {
    __shared__ float sWvT[ND][260];
    __shared__ float sCent[NC * ND];
    __shared__ float sV[16][ND + 1];
    __shared__ float sRout[16][NC];
    const int t = threadIdx.x;
    {
        #pragma unroll
        for (int q = 0; q < 8; q++) {
            int id = t + q * 256;
            int k = id >> 3, c4 = (id & 7) * 4;
            float4 w = ((const float4*)Wv)[id];
            sWvT[c4 + 0][k] = w.x;
            sWvT[c4 + 1][k] = w.y;
            sWvT[c4 + 2][k] = w.z;
            sWvT[c4 + 3][k] = w.w;
        }
        if (t < 64) ((float4*)sCent)[t] = ((const float4*)centers)[t];
    }
    __syncthreads();
    const int r = t >> 4, cp = t & 15;
    const int row = blockIdx.x * 16 + r;
    float a0 = bv[cp], a1 = bv[cp + 16];
    const float4* f4 = (const float4*)(feats + row * NH);
    for (int k4 = 0; k4 < NH / 4; k4++) {
        float4 f = f4[k4];
        float4 w0 = *(const float4*)(&sWvT[cp][k4 * 4]);
        float4 w1 = *(const float4*)(&sWvT[cp + 16][k4 * 4]);
        a0 = fmaf(f.x, w0.x, a0); a1 = fmaf(f.x, w1.x, a1);
        a0 = fmaf(f.y, w0.y, a0); a1 = fmaf(f.y, w1.y, a1);
        a0 = fmaf(f.z, w0.z, a0); a1 = fmaf(f.z, w1.z, a1);
        a0 = fmaf(f.w, w0.w, a0); a1 = fmaf(f.w, w1.w, a1);
    }
    sV[r][cp] = a0; sV[r][cp + 16] = a1;
    __syncthreads();
    if (t < 16) {
        const int rr = t, grow = blockIdx.x * 16 + rr;
        float sc[NC];
        float m = -3.4e38f; int kmax = 0;
        #pragma unroll
        for (int c = 0; c < NC; c++) {
            float acc = 0.f;
            #pragma unroll
            for (int k = 0; k < ND; k++) acc = fmaf(sV[rr][k], sCent[c * ND + k], acc);
            acc = acc / 5.65685424949238f;
            sc[c] = acc;
            if (acc > m) { m = acc; kmax = c; }
        }
        float s = 0.f;
        #pragma unroll
        for (int c = 0; c < NC; c++) { float e = expf(sc[c] - m); sc[c] = e; s += e; }
        float inv = 1.f / s;
        #pragma unroll
        for (int c = 0; c < NC; c++) {
            float rv = sc[c] * inv;
            sRout[rr][c] = rv;
            out[OFF_ROUTER + grow * NC + c] = rv;
        }
        out[OFF_KCHART + grow] = (float)kmax;
    }
    __syncthreads();
    #pragma unroll
    for (int j = 0; j < 2; j++) {
        int col = cp + j * 16;
        float cb = 0.f;
        #pragma unroll
        for (int c = 0; c < NC; c++) cb = fmaf(sRout[r][c], sCent[c * ND + col], cb);
        float vl = sV[r][col] - cb;
        out[OFF_CBAR + row * ND + col] = cb;
        out[OFF_VLOC + row * ND + col] = vl;
        vloc_ws[row * ND + col] = vl;
    }
}

// ---------------------------------------------------------------------------
// vq_chart: block = 64 rows x 1 chart. grid 512 (rowtile, chart).
// ---------------------------------------------------------------------------
__global__ __launch_bounds__(256)
void vq_chart(const float* __restrict__ codebook, const float* __restrict__ vloc_ws,
              const float* __restrict__ Ws1, const float* __restrict__ bs1,
              const float* __restrict__ Ws2, const float* __restrict__ bs2,
              float* __restrict__ out, float* __restrict__ loss_partial) {
    __shared__ float sCB[NK][36];
    __shared__ float sV[64][36];
    __shared__ float sBest[8][64];
    __shared__ int   sBidx[8][64];
    __shared__ int   sSel[64];
    __shared__ float sRoutv[64];
    __shared__ float sPscale[64];
    __shared__ float sLossArr[64];
    __shared__ float sWs1[ND][17];
    __shared__ float sWs2[NHS][33];
    __shared__ float sbs1[NHS], sbs2v[ND];
    const int t = threadIdx.x;
    const int c = blockIdx.x & 7;
    const int row0 = (blockIdx.x >> 3) * 64;

    {
        const float4* src = (const float4*)(codebook + c * NK * ND);
        #pragma unroll
        for (int q = 0; q < 8; q++) {
            int id = t + q * 256;
            int code = id >> 3, kq = (id & 7) * 4;
            *(float4*)(&sCB[code][kq]) = src[id];
        }
        #pragma unroll
        for (int q = 0; q < 2; q++) {
            int id = t + q * 256;
            int rr = id >> 3, kq = (id & 7) * 4;
            *(float4*)(&sV[rr][kq]) = ((const float4*)(vloc_ws + row0 * ND))[id];
        }
    }
    if (t < 128) {
        float4 w = ((const float4*)Ws1)[t];
        int k = t >> 2, o = (t & 3) * 4;
        sWs1[k][o] = w.x; sWs1[k][o+1] = w.y; sWs1[k][o+2] = w.z; sWs1[k][o+3] = w.w;
    } else {
        int u = t - 128;
        float4 w = ((const float4*)Ws2)[u];
        int k = u >> 3, o = (u & 7) * 4;
        sWs2[k][o] = w.x; sWs2[k][o+1] = w.y; sWs2[k][o+2] = w.z; sWs2[k][o+3] = w.w;
    }
    if (t < NHS) sbs1[t] = bs1[t];
    else if (t < NHS + ND) sbs2v[t - NHS] = bs2[t - NHS];
    if (t < 64) sRoutv[t] = out[OFF_ROUTER + (row0 + t) * NC + c];
    __syncthreads();

    const int r = t & 31, g = t >> 5;
    float vl0[ND], vl1[ND];
    #pragma unroll
    for (int q = 0; q < 8; q++) {
        float4 a = *(const float4*)(&sV[r][q * 4]);
        vl0[q*4] = a.x; vl0[q*4+1] = a.y; vl0[q*4+2] = a.z; vl0[q*4+3] = a.w;
        float4 b = *(const float4*)(&sV[r + 32][q * 4]);
        vl1[q*4] = b.x; vl1[q*4+1] = b.y; vl1[q*4+2] = b.z; vl1[q*4+3] = b.w;
    }
    float best0 = 3.4e38f, best1 = 3.4e38f;
    int bi0 = 0, bi1 = 0;
    for (int j = 0; j < 32; j++) {
        const int code = g * 32 + j;
        float dot0 = 0.f, dot1 = 0.f, en2 = 0.f;
        #pragma unroll
        for (int q = 0; q < 8; q++) {
            float4 e = *(const float4*)(&sCB[code][q * 4]);
            en2  = fmaf(e.x, e.x, en2);
            dot0 = fmaf(vl0[q*4+0], e.x, dot0); dot1 = fmaf(vl1[q*4+0], e.x, dot1);
            en2  = fmaf(e.y, e.y, en2);
            dot0 = fmaf(vl0[q*4+1], e.y, dot0); dot1 = fmaf(vl1[q*4+1], e.y, dot1);
            en2  = fmaf(e.z, e.z, en2);
            dot0 = fmaf(vl0[q*4+2], e.z, dot0); dot1 = fmaf(vl1[q*4+2], e.z, dot1);
            en2  = fmaf(e.w, e.w, en2);
            dot0 = fmaf(vl0[q*4+3], e.w, dot0); dot1 = fmaf(vl1[q*4+3], e.w, dot1);
        }
        float d0 = en2 - 2.f * dot0;
        float d1 = en2 - 2.f * dot1;
        if (d0 < best0) { best0 = d0; bi0 = code; }
        if (d1 < best1) { best1 = d1; bi1 = code; }
    }
    sBest[g][r] = best0;      sBidx[g][r] = bi0;
    sBest[g][r + 32] = best1; sBidx[g][r + 32] = bi1;
    __syncthreads();
    if (t < 64) {
        float bb = sBest[0][t]; int ii = sBidx[0][t];
        #pragma unroll
        for (int gg = 1; gg < 8; gg++) {
            float v = sBest[gg][t];
            if (v < bb) { bb = v; ii = sBidx[gg][t]; }
        }
        sSel[t] = ii;
        out[OFF_IND + (row0 + t) * NC + c] = (float)ii;
        float vn2 = 0.f;
        #pragma unroll
        for (int k = 0; k < ND; k++) { float v = sV[t][k]; vn2 = fmaf(v, v, vn2); }
        float norm = fmaxf(sqrtf(vn2), 1e-6f);
        sPscale[t] = fminf(0.99f / norm, 1.0f);
    }
    __syncthreads();

    const int i = t & 15, r16 = t >> 4;
    const float b1r = sbs1[i];
    const float bo0 = sbs2v[2*i], bo1 = sbs2v[2*i+1];
    #pragma unroll
    for (int pass = 0; pass < 4; pass++) {
        const int lrow = pass * 16 + r16;
        const int grow = row0 + lrow;
        const int sel = sSel[lrow];
        const float rc = sRoutv[lrow];
        const float ps = sPscale[lrow];
        float acc1 = b1r;
        #pragma unroll
        for (int k = 0; k < ND; k++) {
            float dlt = sV[lrow][k] - sCB[sel][k];
            acc1 = fmaf(dlt, sWs1[k][i], acc1);
        }
        float h = gelu_exact(acc1);
        float a0 = bo0, a1 = bo1;
        #pragma unroll
        for (int k = 0; k < NHS; k++) {
            float s1k = __shfl(h, k, 16);
            a0 = fmaf(s1k, sWs2[k][2*i],   a0);
            a1 = fmaf(s1k, sWs2[k][2*i+1], a1);
        }
        out[OFF_ZNALL + (grow * NC + c) * ND + 2*i]     = a0;
        out[OFF_ZNALL + (grow * NC + c) * ND + 2*i + 1] = a1;
        const float e0 = sCB[sel][2*i], e1 = sCB[sel][2*i+1];
        float yp0 = sV[lrow][2*i] * ps, yp1 = sV[lrow][2*i+1] * ps;
        float d0 = e0 - yp0, d1 = e1 - yp1;
        float sq = fmaf(d0, d0, d1 * d1);
        float xn = fmaf(e0, e0, e1 * e1);
        float yn = fmaf(yp0, yp0, yp1 * yp1);
        #pragma unroll
        for (int m = 1; m < 16; m <<= 1) {
            sq += __shfl_xor(sq, m, 16);
            xn += __shfl_xor(xn, m, 16);
            yn += __shfl_xor(yn, m, 16);
        }
        if (i == 0) {
            float denom = fmaxf((1.f - xn) * (1.f - yn), 1e-6f);
            float arg = fmaxf(1.f + 2.f * sq / denom, 1.f + 1e-6f);
            float dd = acoshf(arg);
            sLossArr[lrow] = dd * dd * rc;
        }
    }
    __syncthreads();
    if (t < 64) {
        float v = sLossArr[t];
        #pragma unroll
        for (int off = 32; off > 0; off >>= 1) v += __shfl_down(v, off, 64);
        if (t == 0) loss_partial[blockIdx.x] = v;
    }
}

// ---------------------------------------------------------------------------
// finalize + loss reduce (block 0): blends + z_n/z_tex/z_geo + K_code.
// ---------------------------------------------------------------------------
__global__ __launch_bounds__(256)
void finalize2_kernel(const float* __restrict__ codebook, const float* __restrict__ vloc_ws,
                      float* __restrict__ out, const float* __restrict__ partials) {
    const int gid = blockIdx.x * 256 + threadIdx.x;
    const int row = gid >> 4;
    const int cp = gid & 15;
    float rout[NC]; int ind[NC];
    #pragma unroll
    for (int cc = 0; cc < NC; cc++) {
        rout[cc] = out[OFF_ROUTER + row * NC + cc];
        ind[cc]  = (int)out[OFF_IND + row * NC + cc];
    }
    float zn0 = 0.f, zn1 = 0.f, zq0 = 0.f, zq1 = 0.f;
    #pragma unroll
    for (int cc = 0; cc < NC; cc++) {
        const float rcc = rout[cc];
        zn0 = fmaf(out[OFF_ZNALL + (row * NC + cc) * ND + 2*cp],     rcc, zn0);
        zn1 = fmaf(out[OFF_ZNALL + (row * NC + cc) * ND + 2*cp + 1], rcc, zn1);
        const float* e = codebook + (cc * NK + ind[cc]) * ND + 2*cp;
        zq0 = fmaf(e[0], rcc, zq0);
        zq1 = fmaf(e[1], rcc, zq1);
    }
    const float v0 = vloc_ws[row * ND + 2*cp], v1 = vloc_ws[row * ND + 2*cp + 1];
    const float cb0 = out[OFF_CBAR + row * ND + 2*cp];
    const float cb1 = out[OFF_CBAR + row * ND + 2*cp + 1];
    out[OFF_ZN   + row * ND + 2*cp]     = zn0;
    out[OFF_ZN   + row * ND + 2*cp + 1] = zn1;
    out[OFF_ZTEX + row * ND + 2*cp]     = v0 - zq0 - zn0;
    out[OFF_ZTEX + row * ND + 2*cp + 1] = v1 - zq1 - zn1;
    out[OFF_ZGEO + row * ND + 2*cp]     = cb0 + zq0 + zn0;
    out[OFF_ZGEO + row * ND + 2*cp + 1] = cb1 + zq1 + zn1;
    if (cp == 0) {
        int kc = (int)out[OFF_KCHART + row];
        out[OFF_KCODE + row] = out[OFF_IND + row * NC + kc];
    }
    if (blockIdx.x == 0) {
        __shared__ float sTmp[4];
        const int t = threadIdx.x;
        float v = partials[t] + partials[t + 256];
        #pragma unroll
        for (int off = 32; off > 0; off >>= 1) v += __shfl_down(v, off, 64);
        if ((t & 63) == 0) sTmp[t >> 6] = v;
        __syncthreads();
        if (t == 0) out[OFF_LOSS] = 1.25f * (sTmp[0] + sTmp[1] + sTmp[2] + sTmp[3]) / 4096.f;
    }
}

extern "C" void kernel_launch(void* const* d_in, const int* in_sizes, int n_in,
                              void* d_out, int out_size, void* d_ws, size_t ws_size,
                              hipStream_t stream) {
    const float* x        = (const float*)d_in[0];
    const float* W1       = (const float*)d_in[1];
    const float* b1       = (const float*)d_in[2];
    const float* W2       = (const float*)d_in[3];
    const float* b2       = (const float*)d_in[4];
    const float* Wv       = (const float*)d_in[5];
    const float* bv       = (const float*)d_in[6];
    const float* centers  = (const float*)d_in[7];
    const float* codebook = (const float*)d_in[8];
    const float* Ws1      = (const float*)d_in[9];
    const float* bs1      = (const float*)d_in[10];
    const float* Ws2      = (const float*)d_in[11];
    const float* bs2      = (const float*)d_in[12];
    float* out = (float*)d_out;
    float* ws  = (float*)d_ws;

    float* h1       = ws;                                // 4096*256
    float* feats    = ws + 4096 * 256;                   // 4096*256
    float* vloc     = ws + 2 * 4096 * 256;               // 4096*32
    float* partials = ws + 2 * 4096 * 256 + 4096 * 32;   // 512

    gemm_bias_gelu<128><<<dim3(4, 64), dim3(256), 0, stream>>>(x, W1, b1, h1);
    gemm_bias_gelu<256><<<dim3(4, 64), dim3(256), 0, stream>>>(h1, W2, b2, feats);
    router_kernel<<<dim3(256), dim3(256), 0, stream>>>(feats, Wv, bv, centers, out, vloc);
    vq_chart<<<dim3(512), dim3(256), 0, stream>>>(codebook, vloc, Ws1, bs1, Ws2, bs2, out, partials);
    finalize2_kernel<<<dim3(256), dim3(256), 0, stream>>>(codebook, vloc, out, partials);
}

// Round 6
// 59.955 us; speedup vs baseline: 1.5429x; 1.1608x over previous
//
#include <hip/hip_runtime.h>
#include <math.h>

#define NB 4096
#define NIN 128
#define NH 256
#define ND 32
#define NC 8
#define NK 256
#define NHS 16

// output offsets (in floats), concatenated in reference return order
#define OFF_KCHART 0
#define OFF_KCODE  4096
#define OFF_ZN     8192
#define OFF_ZTEX   (OFF_ZN + 4096*32)        // 139264
#define OFF_ROUTER (OFF_ZTEX + 4096*32)      // 270336 (float4-aligned)
#define OFF_ZGEO   (OFF_ROUTER + 4096*8)     // 303104
#define OFF_LOSS   (OFF_ZGEO + 4096*32)      // 434176
#define OFF_IND    (OFF_LOSS + 1)            // 434177 (odd -> scalar access only)
#define OFF_ZNALL  (OFF_IND + 4096*8)        // 466945 (odd -> scalar access only)
#define OFF_CBAR   (OFF_ZNALL + 4096*8*32)   // 1515521 (odd -> scalar)
#define OFF_VLOC   (OFF_CBAR + 4096*32)      // 1646593 (odd -> scalar)

__device__ __forceinline__ float gelu_exact(float x) {
    return x * (erff(x / 1.41421356237309504f) + 1.0f) * 0.5f;
}

// ---------------------------------------------------------------------------
// GEMM v3: out = gelu(A[M][K] @ W[K][256] + b). 32x64 tile, 256 thr, 2x4
// micro, grid 512 (2 blocks/CU -> 2 waves/SIMD). B in LDS (dbuf, one
// barrier/tile); A streamed global->regs (2 rows, chunk=4k, depth 2).
// ---------------------------------------------------------------------------
template<int K>
__global__ __launch_bounds__(256)
void gemm_bias_gelu(const float* __restrict__ A, const float* __restrict__ W,
                    const float* __restrict__ bias, float* __restrict__ out) {
    const int N = 256;
    __shared__ float sB[2][32][68];
    const int t  = threadIdx.x;
    const int n0 = blockIdx.x * 64;
    const int r0 = blockIdx.y * 32;
    const int ty = t >> 4, tx = t & 15;
    const int bk = t >> 4, bc = t & 15;

    float4 bias4 = *(const float4*)(bias + n0 + tx * 4);

    float4 pb0 = *(const float4*)(W + bk * N + n0 + bc * 4);
    float4 pb1 = *(const float4*)(W + (bk + 16) * N + n0 + bc * 4);

    const float* Ab0 = A + (r0 + ty * 2 + 0) * K;
    const float* Ab1 = A + (r0 + ty * 2 + 1) * K;
    float ac[2][4], an[2][4];
    {
        float4 c0 = *(const float4*)(Ab0 + 0), c1 = *(const float4*)(Ab1 + 0);
        ac[0][0]=c0.x; ac[0][1]=c0.y; ac[0][2]=c0.z; ac[0][3]=c0.w;
        ac[1][0]=c1.x; ac[1][1]=c1.y; ac[1][2]=c1.z; ac[1][3]=c1.w;
        float4 d0 = *(const float4*)(Ab0 + 4), d1 = *(const float4*)(Ab1 + 4);
        an[0][0]=d0.x; an[0][1]=d0.y; an[0][2]=d0.z; an[0][3]=d0.w;
        an[1][0]=d1.x; an[1][1]=d1.y; an[1][2]=d1.z; an[1][3]=d1.w;
    }

    float acc[2][4];
    #pragma unroll
    for (int i = 0; i < 2; i++)
        #pragma unroll
        for (int j = 0; j < 4; j++) acc[i][j] = 0.f;

    int buf = 0;
    for (int kk = 0; kk < K; kk += 32) {
        *(float4*)(&sB[buf][bk][bc*4])    = pb0;
        *(float4*)(&sB[buf][bk+16][bc*4]) = pb1;
        __syncthreads();
        if (kk + 32 < K) {
            pb0 = *(const float4*)(W + (kk + 32 + bk) * N + n0 + bc * 4);
            pb1 = *(const float4*)(W + (kk + 32 + bk + 16) * N + n0 + bc * 4);
        }
        #pragma unroll
        for (int c = 0; c < 8; c++) {
            int knext = kk + (c + 2) * 4;
            if (knext > K - 4) knext = K - 4;
            float4 p0 = *(const float4*)(Ab0 + knext);
            float4 p1 = *(const float4*)(Ab1 + knext);
            #pragma unroll
            for (int u = 0; u < 4; u++) {
                float4 bv = *(const float4*)(&sB[buf][c * 4 + u][tx * 4]);
                float bb[4] = {bv.x, bv.y, bv.z, bv.w};
                #pragma unroll
                for (int j = 0; j < 4; j++) {
                    acc[0][j] = fmaf(ac[0][u], bb[j], acc[0][j]);
                    acc[1][j] = fmaf(ac[1][u], bb[j], acc[1][j]);
                }
            }
            #pragma unroll
            for (int u = 0; u < 4; u++) { ac[0][u] = an[0][u]; ac[1][u] = an[1][u]; }
            an[0][0]=p0.x; an[0][1]=p0.y; an[0][2]=p0.z; an[0][3]=p0.w;
            an[1][0]=p1.x; an[1][1]=p1.y; an[1][2]=p1.z; an[1][3]=p1.w;
        }
        buf ^= 1;
    }
    float bb4[4] = {bias4.x, bias4.y, bias4.z, bias4.w};
    #pragma unroll
    for (int i = 0; i < 2; i++) {
        int row = r0 + ty * 2 + i;
        float4 o;
        float* op = (float*)&o;
        #pragma unroll
        for (int j = 0; j < 4; j++) op[j] = gelu_exact(acc[i][j] + bb4[j]);
        *(float4*)(out + row * N + n0 + tx * 4) = o;
    }
}

// ---------------------------------------------------------------------------
// router v2: 8 rows/block, grid 512, one col/thread (r=t>>5, cp=t&31).
// v = feats@Wv + bv ; softmax router ; K_chart ; c_bar ; v_local
// ---------------------------------------------------------------------------
__global__ __launch_bounds__(256)
void router_kernel(const float* __restrict__ feats, const float* __restrict__ Wv,
                   const float* __restrict__ bv, const float* __restrict__ centers,
                   float* __restrict__ out, float* __restrict__ vloc_ws) {
    __shared__ float sWvT[ND][260];   // [col][k], stride 260 = 4*65 (bw-floor ok)
    __shared__ float sCent[NC * ND];
    __shared__ float sV[8][ND + 2];
    __shared__ float sScore[8][NC];
    __shared__ float sRout[8][NC];
    const int t = threadIdx.x;
    const int row0 = blockIdx.x * 8;
    {
        #pragma unroll
        for (int q = 0; q < 8; q++) {
            int id = t + q * 256;
            int k = id >> 3, c4 = (id & 7) * 4;
            float4 w = ((const float4*)Wv)[id];
            sWvT[c4 + 0][k] = w.x;
            sWvT[c4 + 1][k] = w.y;
            sWvT[c4 + 2][k] = w.z;
            sWvT[c4 + 3][k] = w.w;
        }
        if (t < 64) ((float4*)sCent)[t] = ((const float4*)centers)[t];
    }
    __syncthreads();
    const int r = t >> 5, cp = t & 31;
    const int row = row0 + r;
    float a0 = bv[cp];
    const float4* f4 = (const float4*)(feats + row * NH);
    for (int k4 = 0; k4 < NH / 4; k4++) {
        float4 f = f4[k4];
        float4 w = *(const float4*)(&sWvT[cp][k4 * 4]);
        a0 = fmaf(f.x, w.x, a0);
        a0 = fmaf(f.y, w.y, a0);
        a0 = fmaf(f.z, w.z, a0);
        a0 = fmaf(f.w, w.w, a0);
    }
    sV[r][cp] = a0;
    __syncthreads();
    if (t < 64) {
        int rr = t >> 3, c = t & 7;
        float s = 0.f;
        #pragma unroll
        for (int k = 0; k < ND; k++) s = fmaf(sV[rr][k], sCent[c * ND + k], s);
        sScore[rr][c] = s / 5.65685424949238f;
    }
    __syncthreads();
    if (t < 8) {
        const int rr = t, grow = row0 + rr;
        float sc[NC];
        float m = -3.4e38f; int kmax = 0;
        #pragma unroll
        for (int c = 0; c < NC; c++) {
            float s = sScore[rr][c];
            sc[c] = s;
            if (s > m) { m = s; kmax = c; }
        }
        float ssum = 0.f;
        #pragma unroll
        for (int c = 0; c < NC; c++) { float e = expf(sc[c] - m); sc[c] = e; ssum += e; }
        float inv = 1.f / ssum;
        #pragma unroll
        for (int c = 0; c < NC; c++) {
            float rv = sc[c] * inv;
            sRout[rr][c] = rv;
            out[OFF_ROUTER + grow * NC + c] = rv;
        }
        out[OFF_KCHART + grow] = (float)kmax;
    }
    __syncthreads();
    {
        const int col = cp;
        float cb = 0.f;
        #pragma unroll
        for (int c = 0; c < NC; c++) cb = fmaf(sRout[r][c], sCent[c * ND + col], cb);
        float vl = sV[r][col] - cb;
        out[OFF_CBAR + row * ND + col] = cb;
        out[OFF_VLOC + row * ND + col] = vl;
        vloc_ws[row * ND + col] = vl;
    }
}

// ---------------------------------------------------------------------------
// vq_chart: block = 64 rows x 1 chart. grid 512. |e|^2 precomputed in sEn2.
// ---------------------------------------------------------------------------
__global__ __launch_bounds__(256)
void vq_chart(const float* __restrict__ codebook, const float* __restrict__ vloc_ws,
              const float* __restrict__ Ws1, const float* __restrict__ bs1,
              const float* __restrict__ Ws2, const float* __restrict__ bs2,
              float* __restrict__ out, float* __restrict__ loss_partial) {
    __shared__ float sCB[NK][36];
    __shared__ float sEn2[NK];
    __shared__ float sV[64][36];
    __shared__ float sBest[8][64];
    __shared__ int   sBidx[8][64];
    __shared__ int   sSel[64];
    __shared__ float sRoutv[64];
    __shared__ float sPscale[64];
    __shared__ float sLossArr[64];
    __shared__ float sWs1[ND][17];
    __shared__ float sWs2[NHS][33];
    __shared__ float sbs1[NHS], sbs2v[ND];
    const int t = threadIdx.x;
    const int c = blockIdx.x & 7;
    const int row0 = (blockIdx.x >> 3) * 64;

    {
        const float4* src = (const float4*)(codebook + c * NK * ND);
        #pragma unroll
        for (int q = 0; q < 8; q++) {
            int id = t + q * 256;
            int code = id >> 3, kq = (id & 7) * 4;
            *(float4*)(&sCB[code][kq]) = src[id];
        }
        #pragma unroll
        for (int q = 0; q < 2; q++) {
            int id = t + q * 256;
            int rr = id >> 3, kq = (id & 7) * 4;
            *(float4*)(&sV[rr][kq]) = ((const float4*)(vloc_ws + row0 * ND))[id];
        }
    }
    if (t < 128) {
        float4 w = ((const float4*)Ws1)[t];
        int k = t >> 2, o = (t & 3) * 4;
        sWs1[k][o] = w.x; sWs1[k][o+1] = w.y; sWs1[k][o+2] = w.z; sWs1[k][o+3] = w.w;
    } else {
        int u = t - 128;
        float4 w = ((const float4*)Ws2)[u];
        int k = u >> 3, o = (u & 7) * 4;
        sWs2[k][o] = w.x; sWs2[k][o+1] = w.y; sWs2[k][o+2] = w.z; sWs2[k][o+3] = w.w;
    }
    if (t < NHS) sbs1[t] = bs1[t];
    else if (t < NHS + ND) sbs2v[t - NHS] = bs2[t - NHS];
    if (t < 64) sRoutv[t] = out[OFF_ROUTER + (row0 + t) * NC + c];
    __syncthreads();
    // per-code squared norms (same FMA order as inline before)
    {
        float s = 0.f;
        #pragma unroll
        for (int q = 0; q < 8; q++) {
            float4 e = *(const float4*)(&sCB[t][q * 4]);
            s = fmaf(e.x, e.x, s); s = fmaf(e.y, e.y, s);
            s = fmaf(e.z, e.z, s); s = fmaf(e.w, e.w, s);
        }
        sEn2[t] = s;
    }
    __syncthreads();

    const int r = t & 31, g = t >> 5;
    float vl0[ND], vl1[ND];
    #pragma unroll
    for (int q = 0; q < 8; q++) {
        float4 a = *(const float4*)(&sV[r][q * 4]);
        vl0[q*4] = a.x; vl0[q*4+1] = a.y; vl0[q*4+2] = a.z; vl0[q*4+3] = a.w;
        float4 b = *(const float4*)(&sV[r + 32][q * 4]);
        vl1[q*4] = b.x; vl1[q*4+1] = b.y; vl1[q*4+2] = b.z; vl1[q*4+3] = b.w;
    }
    float best0 = 3.4e38f, best1 = 3.4e38f;
    int bi0 = 0, bi1 = 0;
    for (int j = 0; j < 32; j++) {
        const int code = g * 32 + j;
        float dot0 = 0.f, dot1 = 0.f;
        #pragma unroll
        for (int q = 0; q < 8; q++) {
            float4 e = *(const float4*)(&sCB[code][q * 4]);
            dot0 = fmaf(vl0[q*4+0], e.x, dot0); dot1 = fmaf(vl1[q*4+0], e.x, dot1);
            dot0 = fmaf(vl0[q*4+1], e.y, dot0); dot1 = fmaf(vl1[q*4+1], e.y, dot1);
            dot0 = fmaf(vl0[q*4+2], e.z, dot0); dot1 = fmaf(vl1[q*4+2], e.z, dot1);
            dot0 = fmaf(vl0[q*4+3], e.w, dot0); dot1 = fmaf(vl1[q*4+3], e.w, dot1);
        }
        const float en2 = sEn2[code];
        float d0 = en2 - 2.f * dot0;
        float d1 = en2 - 2.f * dot1;
        if (d0 < best0) { best0 = d0; bi0 = code; }
        if (d1 < best1) { best1 = d1; bi1 = code; }
    }
    sBest[g][r] = best0;      sBidx[g][r] = bi0;
    sBest[g][r + 32] = best1; sBidx[g][r + 32] = bi1;
    __syncthreads();
    if (t < 64) {
        float bb = sBest[0][t]; int ii = sBidx[0][t];
        #pragma unroll
        for (int gg = 1; gg < 8; gg++) {
            float v = sBest[gg][t];
            if (v < bb) { bb = v; ii = sBidx[gg][t]; }
        }
        sSel[t] = ii;
        out[OFF_IND + (row0 + t) * NC + c] = (float)ii;
        float vn2 = 0.f;
        #pragma unroll
        for (int k = 0; k < ND; k++) { float v = sV[t][k]; vn2 = fmaf(v, v, vn2); }
        float norm = fmaxf(sqrtf(vn2), 1e-6f);
        sPscale[t] = fminf(0.99f / norm, 1.0f);
    }
    __syncthreads();

    const int i = t & 15, r16 = t >> 4;
    const float b1r = sbs1[i];
    const float bo0 = sbs2v[2*i], bo1 = sbs2v[2*i+1];
    #pragma unroll
    for (int pass = 0; pass < 4; pass++) {
        const int lrow = pass * 16 + r16;
        const int grow = row0 + lrow;
        const int sel = sSel[lrow];
        const float rc = sRoutv[lrow];
        const float ps = sPscale[lrow];
        float acc1 = b1r;
        #pragma unroll
        for (int k = 0; k < ND; k++) {
            float dlt = sV[lrow][k] - sCB[sel][k];
            acc1 = fmaf(dlt, sWs1[k][i], acc1);
        }
        float h = gelu_exact(acc1);
        float a0 = bo0, a1 = bo1;
        #pragma unroll
        for (int k = 0; k < NHS; k++) {
            float s1k = __shfl(h, k, 16);
            a0 = fmaf(s1k, sWs2[k][2*i],   a0);
            a1 = fmaf(s1k, sWs2[k][2*i+1], a1);
        }
        out[OFF_ZNALL + (grow * NC + c) * ND + 2*i]     = a0;
        out[OFF_ZNALL + (grow * NC + c) * ND + 2*i + 1] = a1;
        const float e0 = sCB[sel][2*i], e1 = sCB[sel][2*i+1];
        float yp0 = sV[lrow][2*i] * ps, yp1 = sV[lrow][2*i+1] * ps;
        float d0 = e0 - yp0, d1 = e1 - yp1;
        float sq = fmaf(d0, d0, d1 * d1);
        float xn = fmaf(e0, e0, e1 * e1);
        float yn = fmaf(yp0, yp0, yp1 * yp1);
        #pragma unroll
        for (int m = 1; m < 16; m <<= 1) {
            sq += __shfl_xor(sq, m, 16);
            xn += __shfl_xor(xn, m, 16);
            yn += __shfl_xor(yn, m, 16);
        }
        if (i == 0) {
            float denom = fmaxf((1.f - xn) * (1.f - yn), 1e-6f);
            float arg = fmaxf(1.f + 2.f * sq / denom, 1.f + 1e-6f);
            float dd = acoshf(arg);
            sLossArr[lrow] = dd * dd * rc;
        }
    }
    __syncthreads();
    if (t < 64) {
        float v = sLossArr[t];
        #pragma unroll
        for (int off = 32; off > 0; off >>= 1) v += __shfl_down(v, off, 64);
        if (t == 0) loss_partial[blockIdx.x] = v;
    }
}

// ---------------------------------------------------------------------------
// finalize v2: one col/thread (131072 threads, grid 512) + loss reduce blk 0.
// ---------------------------------------------------------------------------
__global__ __launch_bounds__(256)
void finalize2_kernel(const float* __restrict__ codebook, const float* __restrict__ vloc_ws,
                      float* __restrict__ out, const float* __restrict__ partials) {
    const int gid = blockIdx.x * 256 + threadIdx.x;
    const int row = gid >> 5;
    const int col = gid & 31;
    float rout[NC]; int ind[NC];
    #pragma unroll
    for (int cc = 0; cc < NC; cc++) {
        rout[cc] = out[OFF_ROUTER + row * NC + cc];
        ind[cc]  = (int)out[OFF_IND + row * NC + cc];
    }
    float zn = 0.f, zq = 0.f;
    #pragma unroll
    for (int cc = 0; cc < NC; cc++) {
        const float rcc = rout[cc];
        zn = fmaf(out[OFF_ZNALL + (row * NC + cc) * ND + col], rcc, zn);
        zq = fmaf(codebook[(cc * NK + ind[cc]) * ND + col], rcc, zq);
    }
    const float vl = vloc_ws[row * ND + col];
    const float cb = out[OFF_CBAR + row * ND + col];
    out[OFF_ZN   + row * ND + col] = zn;
    out[OFF_ZTEX + row * ND + col] = vl - zq - zn;
    out[OFF_ZGEO + row * ND + col] = cb + zq + zn;
    if (col == 0) {
        int kc = (int)out[OFF_KCHART + row];
        out[OFF_KCODE + row] = out[OFF_IND + row * NC + kc];
    }
    if (blockIdx.x == 0) {
        __shared__ float sTmp[4];
        const int t = threadIdx.x;
        float v = partials[t] + partials[t + 256];
        #pragma unroll
        for (int off = 32; off > 0; off >>= 1) v += __shfl_down(v, off, 64);
        if ((t & 63) == 0) sTmp[t >> 6] = v;
        __syncthreads();
        if (t == 0) out[OFF_LOSS] = 1.25f * (sTmp[0] + sTmp[1] + sTmp[2] + sTmp[3]) / 4096.f;
    }
}

extern "C" void kernel_launch(void* const* d_in, const int* in_sizes, int n_in,
                              void* d_out, int out_size, void* d_ws, size_t ws_size,
                              hipStream_t stream) {
    const float* x        = (const float*)d_in[0];
    const float* W1       = (const float*)d_in[1];
    const float* b1       = (const float*)d_in[2];
    const float* W2       = (const float*)d_in[3];
    const float* b2       = (const float*)d_in[4];
    const float* Wv       = (const float*)d_in[5];
    const float* bv       = (const float*)d_in[6];
    const float* centers  = (const float*)d_in[7];
    const float* codebook = (const float*)d_in[8];
    const float* Ws1      = (const float*)d_in[9];
    const float* bs1      = (const float*)d_in[10];
    const float* Ws2      = (const float*)d_in[11];
    const float* bs2      = (const float*)d_in[12];
    float* out = (float*)d_out;
    float* ws  = (float*)d_ws;

    float* h1       = ws;                                // 4096*256
    float* feats    = ws + 4096 * 256;                   // 4096*256
    float* vloc     = ws + 2 * 4096 * 256;               // 4096*32
    float* partials = ws + 2 * 4096 * 256 + 4096 * 32;   // 512

    gemm_bias_gelu<128><<<dim3(4, 128), dim3(256), 0, stream>>>(x, W1, b1, h1);
    gemm_bias_gelu<256><<<dim3(4, 128), dim3(256), 0, stream>>>(h1, W2, b2, feats);
    router_kernel<<<dim3(512), dim3(256), 0, stream>>>(feats, Wv, bv, centers, out, vloc);
    vq_chart<<<dim3(512), dim3(256), 0, stream>>>(codebook, vloc, Ws1, bs1, Ws2, bs2, out, partials);
    finalize2_kernel<<<dim3(512), dim3(256), 0, stream>>>(codebook, vloc, out, partials);
}